// Round 7
// baseline (442.606 us; speedup 1.0000x reference)
//
#include <hip/hip_runtime.h>
#include <cmath>

typedef float vf2 __attribute__((ext_vector_type(2)));

struct G11 { float v[11]; };

#define NB0 12288
#define NB1 3072
#define NB2 768
#define NB3 192
#define NB4 48
#define NPART 16368
#define NREST 4080

// LDS: row-pair interleaved tile + vertical-conv intermediate
struct Smem {
    float4 sAB2[21][43];   // [rowpair][col] = {v1(2r), v2(2r), v1(2r+1), v2(2r+1)}  14448 B
    float4 vrt[16][45];    // [row][col] = {mu1, mu2, css, cs12}; also pool scratch  11520 B
    float red[8];
    int isLast;
};

// vertical tap: row J of the 14-row window feeds outputs i in [J-10, J] & [0,3]
template<int J>
__device__ __forceinline__ void vtap(vf2 m, const float (&g)[11], vf2 (&amu)[4], vf2 (&aq)[4]) {
    vf2 t = m * m;
    vf2 q = { t.x + t.y, m.x * m.y };   // {a^2+b^2, a*b}
#pragma unroll
    for (int i = 0; i < 4; ++i) {
        if (J - i >= 0 && J - i <= 10) {
            vf2 gs = { g[J - i], g[J - i] };
            amu[i] = __builtin_elementwise_fma(gs, m, amu[i]);
            aq[i]  = __builtin_elementwise_fma(gs, q, aq[i]);
        }
    }
}

// horizontal tap: col T of the 14-col window feeds outputs i in [T-10, T] & [0,3]
template<int T>
__device__ __forceinline__ void htap(const float4 V, const float (&g)[11], vf2 (&amu)[4], vf2 (&aq)[4]) {
    vf2 mt = { V.x, V.y }, qt = { V.z, V.w };
#pragma unroll
    for (int i = 0; i < 4; ++i) {
        if (T - i >= 0 && T - i <= 10) {
            vf2 gs = { g[T - i], g[T - i] };
            amu[i] = __builtin_elementwise_fma(gs, mt, amu[i]);
            aq[i]  = __builtin_elementwise_fma(gs, qt, aq[i]);
        }
    }
}

struct PyrOut {
    float *a1, *b1, *a2, *b2, *a3, *b3, *a4, *b4;
};

// ---------------------------------------------------------------------------
// Shared per-level SSIM body. Input images are precomputed per level.
// L == 0 additionally emits the whole pyramid (L1..L4) from its staged tile.
// ---------------------------------------------------------------------------
template<int L>
__device__ __forceinline__ void ssim_body(Smem& sm, int tbx, int tby, int z,
    const float* __restrict__ i1, const float* __restrict__ i2,
    const G11 gw, float2* __restrict__ partials, int pidx, const PyrOut* po)
{
    constexpr int Hl = 512 >> L;
    constexpr int Hv = Hl - 10;
    const int tid = threadIdx.x;
    const int bx = tbx * 32, by = tby * 32;

    float g[11];
#pragma unroll
    for (int j = 0; j < 11; ++j) g[j] = gw.v[j];   // kernarg -> SGPRs

    // ---- stage 42x42 halo tile (zero-padded) into row-pair layout
    {
        const float* p1 = i1 + (size_t)z * Hl * Hl;
        const float* p2 = i2 + (size_t)z * Hl * Hl;
        for (int i = tid; i < 441; i += 256) {
            int rp = i / 21, cp = i - rp * 21, c = 2 * cp;
            int y = by + 2 * rp, x = bx + c;
            float2 a0 = {0.f,0.f}, a1 = a0, b0 = a0, b1 = a0;
            if (y < Hl && x < Hl) {   // y,x even; W even => +1 in range too
                const float* r1p = p1 + (size_t)y * Hl + x;
                a0 = *(const float2*)r1p;
                a1 = *(const float2*)(r1p + Hl);
                const float* r2p = p2 + (size_t)y * Hl + x;
                b0 = *(const float2*)r2p;
                b1 = *(const float2*)(r2p + Hl);
            }
            sm.sAB2[rp][c]     = make_float4(a0.x, b0.x, a1.x, b1.x);
            sm.sAB2[rp][c + 1] = make_float4(a0.y, b0.y, a1.y, b1.y);
        }
    }
    __syncthreads();

    // ---- L0 only: emit the entire pyramid from this block's 32x32 region
    if constexpr (L == 0) {
        float2* pp = (float2*)&sm.vrt[0][0];      // 16x16 float2 scratch (2 KB)
        {   // L1: every thread one pixel
            int py = tid >> 4, px = tid & 15;
            float4 q0 = sm.sAB2[py][2 * px];
            float4 q1 = sm.sAB2[py][2 * px + 1];
            float l1a = 0.25f * ((q0.x + q1.x) + (q0.z + q1.z));
            float l1b = 0.25f * ((q0.y + q1.y) + (q0.w + q1.w));
            size_t o = (size_t)z * 65536 + (size_t)(tby * 16 + py) * 256 + (tbx * 16 + px);
            po->a1[o] = l1a; po->b1[o] = l1b;
            pp[tid] = make_float2(l1a, l1b);      // [py][px]
        }
        __syncthreads();
        if (tid < 64) {                           // wave 0: L2/L3/L4 via shfl
            int y = tid >> 3, x = tid & 7;
            float2 p00 = pp[(2*y)*16 + 2*x],     p01 = pp[(2*y)*16 + 2*x + 1];
            float2 p10 = pp[(2*y+1)*16 + 2*x],   p11 = pp[(2*y+1)*16 + 2*x + 1];
            float l2a = 0.25f * ((p00.x + p01.x) + (p10.x + p11.x));
            float l2b = 0.25f * ((p00.y + p01.y) + (p10.y + p11.y));
            size_t o2 = (size_t)z * 16384 + (size_t)(tby * 8 + y) * 128 + (tbx * 8 + x);
            po->a2[o2] = l2a; po->b2[o2] = l2b;

            int b3 = (16 * (tid >> 2) + 2 * (tid & 3)) & 63;
            float a00 = __shfl(l2a, b3),     a01 = __shfl(l2a, b3 + 1);
            float a10 = __shfl(l2a, b3 + 8), a11 = __shfl(l2a, b3 + 9);
            float c00 = __shfl(l2b, b3),     c01 = __shfl(l2b, b3 + 1);
            float c10 = __shfl(l2b, b3 + 8), c11 = __shfl(l2b, b3 + 9);
            float l3a = 0.25f * ((a00 + a01) + (a10 + a11));
            float l3b = 0.25f * ((c00 + c01) + (c10 + c11));
            if (tid < 16) {
                size_t o3 = (size_t)z * 4096 + (size_t)(tby * 4 + (tid >> 2)) * 64 + (tbx * 4 + (tid & 3));
                po->a3[o3] = l3a; po->b3[o3] = l3b;
            }
            int b4 = (8 * (tid >> 1) + 2 * (tid & 1)) & 63;
            float d00 = __shfl(l3a, b4),     d01 = __shfl(l3a, b4 + 1);
            float d10 = __shfl(l3a, b4 + 4), d11 = __shfl(l3a, b4 + 5);
            float e00 = __shfl(l3b, b4),     e01 = __shfl(l3b, b4 + 1);
            float e10 = __shfl(l3b, b4 + 4), e11 = __shfl(l3b, b4 + 5);
            float l4a = 0.25f * ((d00 + d01) + (d10 + d11));
            float l4b = 0.25f * ((e00 + e01) + (e10 + e11));
            if (tid < 4) {
                size_t o4 = (size_t)z * 1024 + (size_t)(tby * 2 + (tid >> 1)) * 32 + (tbx * 2 + (tid & 1));
                po->a4[o4] = l4a; po->b4[o4] = l4b;
            }
        }
        __syncthreads();   // pool scratch (in vrt) reads done before vert conv
    }

    float ssim_l = 0.f, cs_l = 0.f;

#pragma unroll
    for (int p = 0; p < 2; ++p) {
        if (p) __syncthreads();   // vrt overwrite vs previous horiz reads

        // ---- vertical conv, rows [16p,16p+16): 42 cols x 4 chunks x 4 rows
        if (tid < 168) {
            int c = tid % 42, ch = tid / 42;
            int rp0 = 8 * p + 2 * ch;
            // batch all 7 window reads first (single waitcnt, no serial chains)
            float4 Q[7];
#pragma unroll
            for (int k = 0; k < 7; ++k) Q[k] = sm.sAB2[rp0 + k][c];
            vf2 amu[4], aq[4];
#pragma unroll
            for (int i = 0; i < 4; ++i) { amu[i] = (vf2){0.f,0.f}; aq[i] = (vf2){0.f,0.f}; }
#define VPAIR(K) { vtap<2*(K)>((vf2){Q[K].x, Q[K].y}, g, amu, aq);    \
                   vtap<2*(K)+1>((vf2){Q[K].z, Q[K].w}, g, amu, aq); }
            VPAIR(0) VPAIR(1) VPAIR(2) VPAIR(3) VPAIR(4) VPAIR(5) VPAIR(6)
#undef VPAIR
            int r0 = 4 * ch;
#pragma unroll
            for (int i = 0; i < 4; ++i)
                sm.vrt[r0 + i][c] = make_float4(amu[i].x, amu[i].y, aq[i].x, aq[i].y);
        }
        __syncthreads();

        // ---- horizontal conv + SSIM: 16 rows x 8 octs x 4 cols
        if (tid < 128) {
            int row = tid >> 3, oct = tid & 7, c0 = 4 * oct;
            int oy = by + 16 * p + row;
            // batch all 14 window reads first
            float4 V[14];
#pragma unroll
            for (int t = 0; t < 14; ++t) V[t] = sm.vrt[row][c0 + t];
            vf2 amu[4], aq[4];
#pragma unroll
            for (int i = 0; i < 4; ++i) { amu[i] = (vf2){0.f,0.f}; aq[i] = (vf2){0.f,0.f}; }
#define HT(T) htap<(T)>(V[T], g, amu, aq);
            HT(0) HT(1) HT(2) HT(3) HT(4) HT(5) HT(6)
            HT(7) HT(8) HT(9) HT(10) HT(11) HT(12) HT(13)
#undef HT
            if (oy < Hv) {
#pragma unroll
                for (int i = 0; i < 4; ++i) {
                    int ox = bx + c0 + i;
                    if (ox < Hv) {
                        vf2 mu = amu[i], qq = aq[i];
                        float ab = mu.x * mu.y;
                        vf2 t = mu * mu;
                        float aabb = t.x + t.y;
                        float n1 = fmaf(2.f, ab, 0.0004f);
                        float d1 = aabb + 0.0004f;
                        float v1 = fmaf(2.f, qq.y - ab, 0.0036f);
                        float v2 = (qq.x - aabb) + 0.0036f;
                        float rden = __builtin_amdgcn_rcpf(d1 * v2);
                        cs_l   = fmaf(v1 * d1, rden, cs_l);
                        ssim_l = fmaf(n1 * v1, rden, ssim_l);
                    }
                }
            }
        }
    }

    // ---- block reduction (4 waves) -> one float2 per block
#pragma unroll
    for (int off = 32; off > 0; off >>= 1) {
        ssim_l += __shfl_down(ssim_l, off);
        cs_l   += __shfl_down(cs_l, off);
    }
    int wave = tid >> 6, lane = tid & 63;
    if (lane == 0) { sm.red[wave] = ssim_l; sm.red[4 + wave] = cs_l; }
    __syncthreads();
    if (tid == 0) {
        float ss = sm.red[0] + sm.red[1] + sm.red[2] + sm.red[3];
        float cc = sm.red[4] + sm.red[5] + sm.red[6] + sm.red[7];
        partials[pidx] = make_float2(ss, cc);
    }
}

// ---------------------------------------------------------------------------
__global__ __launch_bounds__(256, 6) void ssim_l0_kernel(
    const float* __restrict__ img1, const float* __restrict__ img2,
    const G11 gw, float2* __restrict__ partials, int* __restrict__ counter,
    const PyrOut po)
{
    __shared__ Smem sm;
    if (blockIdx.x == 0 && blockIdx.y == 0 && blockIdx.z == 0 && threadIdx.x == 0)
        *counter = 0;   // zeroed before rest kernel (stream order)
    int pidx = ((int)blockIdx.z * 16 + (int)blockIdx.y) * 16 + (int)blockIdx.x;
    ssim_body<0>(sm, blockIdx.x, blockIdx.y, blockIdx.z, img1, img2, gw, partials, pidx, &po);
}

// ---------------------------------------------------------------------------
// rest kernel: SSIM for L1..L4 + last-block final reduction & formula.
// ---------------------------------------------------------------------------
__global__ __launch_bounds__(256, 6) void ssim_rest_kernel(
    const G11 gw, float2* __restrict__ partials, int* __restrict__ counter,
    float* __restrict__ out, const PyrOut po)
{
    __shared__ Smem sm;
    int b = blockIdx.x;
    if (b < 3072) {
        int lb = b;        int z = lb >> 6; int r = lb & 63; int tby = r >> 3; int tbx = r & 7;
        ssim_body<1>(sm, tbx, tby, z, po.a1, po.b1, gw, partials, 12288 + lb, nullptr);
    } else if (b < 3840) {
        int lb = b - 3072; int z = lb >> 4; int r = lb & 15; int tby = r >> 2; int tbx = r & 3;
        ssim_body<2>(sm, tbx, tby, z, po.a2, po.b2, gw, partials, 15360 + lb, nullptr);
    } else if (b < 4032) {
        int lb = b - 3840; int z = lb >> 2; int r = lb & 3;  int tby = r >> 1; int tbx = r & 1;
        ssim_body<3>(sm, tbx, tby, z, po.a3, po.b3, gw, partials, 16128 + lb, nullptr);
    } else {
        int lb = b - 4032;
        ssim_body<4>(sm, 0, 0, lb, po.a4, po.b4, gw, partials, 16320 + lb, nullptr);
    }

    // ---- last block to finish performs the global reduction + formula
    const int tid = threadIdx.x;
    __threadfence();                          // release partials (device scope)
    if (tid == 0) {
        int prev = atomicAdd(counter, 1);
        sm.isLast = (prev == NREST - 1);
    }
    __syncthreads();
    if (!sm.isLast) return;
    __threadfence();                          // acquire all partials

    double* lev = (double*)&sm.vrt[0][0];     // 10 doubles scratch
    double* sred = lev + 16;                  // [4][2]
    const int NB[5]  = {NB0, NB1, NB2, NB3, NB4};
    const int OFF[5] = {0, NB0, NB0 + NB1, NB0 + NB1 + NB2, NB0 + NB1 + NB2 + NB3};
    const int wv = tid >> 6, ln = tid & 63;

    for (int l = 0; l < 5; ++l) {
        double s = 0.0, c = 0.0;
        for (int i = tid; i < NB[l]; i += 256) {
            float2 p = partials[OFF[l] + i];
            s += (double)p.x; c += (double)p.y;
        }
#pragma unroll
        for (int off = 32; off > 0; off >>= 1) {
            s += __shfl_down(s, off);
            c += __shfl_down(c, off);
        }
        if (ln == 0) { sred[wv * 2] = s; sred[wv * 2 + 1] = c; }
        __syncthreads();
        if (tid == 0) {
            double ss = 0.0, cc = 0.0;
            for (int w = 0; w < 4; ++w) { ss += sred[w * 2]; cc += sred[w * 2 + 1]; }
            lev[l] = ss; lev[5 + l] = cc;
        }
        __syncthreads();
    }

    if (tid == 0) {
        const double counts[5] = {
            48.0 * 502.0 * 502.0,
            48.0 * 246.0 * 246.0,
            48.0 * 118.0 * 118.0,
            48.0 * 54.0 * 54.0,
            48.0 * 22.0 * 22.0
        };
        const double w[5] = { (double)0.0448f, (double)0.2856f, (double)0.3001f,
                              (double)0.2363f, (double)0.1333f };
        double prod = 1.0;
        for (int i = 0; i < 5; ++i) prod *= pow(lev[i] / counts[i], w[i]);
        double mcs = lev[9] / counts[4];   // cs of LAST level
        double output = pow(mcs, w[4]) * prod;
        out[0] = (float)(1.0 - output);
    }
}

// ---------------------------------------------------------------------------
extern "C" void kernel_launch(void* const* d_in, const int* in_sizes, int n_in,
                              void* d_out, int out_size, void* d_ws, size_t ws_size,
                              hipStream_t stream) {
    const float* img1 = (const float*)d_in[0];
    const float* img2 = (const float*)d_in[1];
    float* out = (float*)d_out;

    // Gaussian taps on host (double, matches numpy f64 -> f32 cast)
    G11 gw;
    {
        double w[11]; double s = 0.0;
        for (int i = 0; i < 11; ++i) { double x = (double)(i - 5); w[i] = std::exp(-(x * x) / 4.5); s += w[i]; }
        for (int i = 0; i < 11; ++i) gw.v[i] = (float)(w[i] / s);
    }

    char* ws = (char*)d_ws;
    float2* partials = (float2*)ws;                    // 16368 float2 = 131 KB
    int* counter = (int*)(ws + 131072);
    float* base = (float*)(ws + 131072 + 256);
    PyrOut po;
    size_t o = 0;
    po.a1 = base + o; o += (size_t)48 * 65536;
    po.b1 = base + o; o += (size_t)48 * 65536;
    po.a2 = base + o; o += (size_t)48 * 16384;
    po.b2 = base + o; o += (size_t)48 * 16384;
    po.a3 = base + o; o += (size_t)48 * 4096;
    po.b3 = base + o; o += (size_t)48 * 4096;
    po.a4 = base + o; o += (size_t)48 * 1024;
    po.b4 = base + o; o += (size_t)48 * 1024;

    ssim_l0_kernel<<<dim3(16, 16, 48), dim3(256), 0, stream>>>(
        img1, img2, gw, partials, counter, po);

    ssim_rest_kernel<<<dim3(NREST), dim3(256), 0, stream>>>(
        gw, partials, counter, out, po);
}

// Round 8
// 197.157 us; speedup vs baseline: 2.2449x; 2.2449x over previous
//
#include <hip/hip_runtime.h>
#include <cmath>

typedef float vf2 __attribute__((ext_vector_type(2)));

struct G11 { float v[11]; };

#define NB0 12288
#define NB1 3072
#define NB2 768
#define NB3 192
#define NB4 48
#define NPART 16368

// LDS: row-pair interleaved tile + vertical-conv intermediate
struct Smem {
    float4 sAB2[21][43];   // [rowpair][col] = {v1(2r), v2(2r), v1(2r+1), v2(2r+1)}  14448 B
    float4 vrt[16][45];    // [row][col] = {mu1, mu2, css, cs12}; also pool scratch  11520 B
    float red[8];
};

// vertical tap: row J of the 14-row window feeds outputs i in [J-10, J] & [0,3]
template<int J>
__device__ __forceinline__ void vtap(vf2 m, const float (&g)[11], vf2 (&amu)[4], vf2 (&aq)[4]) {
    vf2 t = m * m;
    vf2 q = { t.x + t.y, m.x * m.y };   // {a^2+b^2, a*b}
#pragma unroll
    for (int i = 0; i < 4; ++i) {
        if (J - i >= 0 && J - i <= 10) {
            vf2 gs = { g[J - i], g[J - i] };
            amu[i] = __builtin_elementwise_fma(gs, m, amu[i]);
            aq[i]  = __builtin_elementwise_fma(gs, q, aq[i]);
        }
    }
}

// horizontal tap: col T of the 14-col window feeds outputs i in [T-10, T] & [0,3]
template<int T>
__device__ __forceinline__ void htap(const float4 V, const float (&g)[11], vf2 (&amu)[4], vf2 (&aq)[4]) {
    vf2 mt = { V.x, V.y }, qt = { V.z, V.w };
#pragma unroll
    for (int i = 0; i < 4; ++i) {
        if (T - i >= 0 && T - i <= 10) {
            vf2 gs = { g[T - i], g[T - i] };
            amu[i] = __builtin_elementwise_fma(gs, mt, amu[i]);
            aq[i]  = __builtin_elementwise_fma(gs, qt, aq[i]);
        }
    }
}

struct PyrOut {
    float *a1, *b1, *a2, *b2, *a3, *b3, *a4, *b4;
};

// ---------------------------------------------------------------------------
// Shared per-level SSIM body. Input images are precomputed per level.
// L == 0 additionally emits the whole pyramid (L1..L4) from its staged tile.
// ---------------------------------------------------------------------------
template<int L>
__device__ __forceinline__ void ssim_body(Smem& sm, int tbx, int tby, int z,
    const float* __restrict__ i1, const float* __restrict__ i2,
    const G11 gw, float2* __restrict__ partials, int pidx, const PyrOut* po)
{
    constexpr int Hl = 512 >> L;
    constexpr int Hv = Hl - 10;
    const int tid = threadIdx.x;
    const int bx = tbx * 32, by = tby * 32;

    float g[11];
#pragma unroll
    for (int j = 0; j < 11; ++j) g[j] = gw.v[j];   // kernarg -> SGPRs

    // ---- stage 42x42 halo tile (zero-padded) into row-pair layout
    {
        const float* p1 = i1 + (size_t)z * Hl * Hl;
        const float* p2 = i2 + (size_t)z * Hl * Hl;
        for (int i = tid; i < 441; i += 256) {
            int rp = i / 21, cp = i - rp * 21, c = 2 * cp;
            int y = by + 2 * rp, x = bx + c;
            float2 a0 = {0.f,0.f}, a1 = a0, b0 = a0, b1 = a0;
            if (y < Hl && x < Hl) {   // y,x even; W even => +1 in range too
                const float* r1p = p1 + (size_t)y * Hl + x;
                a0 = *(const float2*)r1p;
                a1 = *(const float2*)(r1p + Hl);
                const float* r2p = p2 + (size_t)y * Hl + x;
                b0 = *(const float2*)r2p;
                b1 = *(const float2*)(r2p + Hl);
            }
            sm.sAB2[rp][c]     = make_float4(a0.x, b0.x, a1.x, b1.x);
            sm.sAB2[rp][c + 1] = make_float4(a0.y, b0.y, a1.y, b1.y);
        }
    }
    __syncthreads();

    // ---- L0 only: emit the entire pyramid from this block's 32x32 region
    if constexpr (L == 0) {
        float2* pp = (float2*)&sm.vrt[0][0];      // 16x16 float2 scratch (2 KB)
        {   // L1: every thread one pixel
            int py = tid >> 4, px = tid & 15;
            float4 q0 = sm.sAB2[py][2 * px];
            float4 q1 = sm.sAB2[py][2 * px + 1];
            float l1a = 0.25f * ((q0.x + q1.x) + (q0.z + q1.z));
            float l1b = 0.25f * ((q0.y + q1.y) + (q0.w + q1.w));
            size_t o = (size_t)z * 65536 + (size_t)(tby * 16 + py) * 256 + (tbx * 16 + px);
            po->a1[o] = l1a; po->b1[o] = l1b;
            pp[tid] = make_float2(l1a, l1b);      // [py][px]
        }
        __syncthreads();
        if (tid < 64) {                           // wave 0: L2/L3/L4 via shfl
            int y = tid >> 3, x = tid & 7;
            float2 p00 = pp[(2*y)*16 + 2*x],     p01 = pp[(2*y)*16 + 2*x + 1];
            float2 p10 = pp[(2*y+1)*16 + 2*x],   p11 = pp[(2*y+1)*16 + 2*x + 1];
            float l2a = 0.25f * ((p00.x + p01.x) + (p10.x + p11.x));
            float l2b = 0.25f * ((p00.y + p01.y) + (p10.y + p11.y));
            size_t o2 = (size_t)z * 16384 + (size_t)(tby * 8 + y) * 128 + (tbx * 8 + x);
            po->a2[o2] = l2a; po->b2[o2] = l2b;

            int b3 = (16 * (tid >> 2) + 2 * (tid & 3)) & 63;
            float a00 = __shfl(l2a, b3),     a01 = __shfl(l2a, b3 + 1);
            float a10 = __shfl(l2a, b3 + 8), a11 = __shfl(l2a, b3 + 9);
            float c00 = __shfl(l2b, b3),     c01 = __shfl(l2b, b3 + 1);
            float c10 = __shfl(l2b, b3 + 8), c11 = __shfl(l2b, b3 + 9);
            float l3a = 0.25f * ((a00 + a01) + (a10 + a11));
            float l3b = 0.25f * ((c00 + c01) + (c10 + c11));
            if (tid < 16) {
                size_t o3 = (size_t)z * 4096 + (size_t)(tby * 4 + (tid >> 2)) * 64 + (tbx * 4 + (tid & 3));
                po->a3[o3] = l3a; po->b3[o3] = l3b;
            }
            int b4 = (8 * (tid >> 1) + 2 * (tid & 1)) & 63;
            float d00 = __shfl(l3a, b4),     d01 = __shfl(l3a, b4 + 1);
            float d10 = __shfl(l3a, b4 + 4), d11 = __shfl(l3a, b4 + 5);
            float e00 = __shfl(l3b, b4),     e01 = __shfl(l3b, b4 + 1);
            float e10 = __shfl(l3b, b4 + 4), e11 = __shfl(l3b, b4 + 5);
            float l4a = 0.25f * ((d00 + d01) + (d10 + d11));
            float l4b = 0.25f * ((e00 + e01) + (e10 + e11));
            if (tid < 4) {
                size_t o4 = (size_t)z * 1024 + (size_t)(tby * 2 + (tid >> 1)) * 32 + (tbx * 2 + (tid & 1));
                po->a4[o4] = l4a; po->b4[o4] = l4b;
            }
        }
        __syncthreads();   // pool scratch (in vrt) reads done before vert conv
    }

    float ssim_l = 0.f, cs_l = 0.f;

#pragma unroll
    for (int p = 0; p < 2; ++p) {
        if (p) __syncthreads();   // vrt overwrite vs previous horiz reads

        // ---- vertical conv, rows [16p,16p+16): 42 cols x 4 chunks x 4 rows
        if (tid < 168) {
            int c = tid % 42, ch = tid / 42;
            int rp0 = 8 * p + 2 * ch;
            // batch all 7 window reads first (single waitcnt, no serial chains)
            float4 Q[7];
#pragma unroll
            for (int k = 0; k < 7; ++k) Q[k] = sm.sAB2[rp0 + k][c];
            vf2 amu[4], aq[4];
#pragma unroll
            for (int i = 0; i < 4; ++i) { amu[i] = (vf2){0.f,0.f}; aq[i] = (vf2){0.f,0.f}; }
#define VPAIR(K) { vtap<2*(K)>((vf2){Q[K].x, Q[K].y}, g, amu, aq);    \
                   vtap<2*(K)+1>((vf2){Q[K].z, Q[K].w}, g, amu, aq); }
            VPAIR(0) VPAIR(1) VPAIR(2) VPAIR(3) VPAIR(4) VPAIR(5) VPAIR(6)
#undef VPAIR
            int r0 = 4 * ch;
#pragma unroll
            for (int i = 0; i < 4; ++i)
                sm.vrt[r0 + i][c] = make_float4(amu[i].x, amu[i].y, aq[i].x, aq[i].y);
        }
        __syncthreads();

        // ---- horizontal conv + SSIM: 16 rows x 8 octs x 4 cols
        if (tid < 128) {
            int row = tid >> 3, oct = tid & 7, c0 = 4 * oct;
            int oy = by + 16 * p + row;
            // batch all 14 window reads first
            float4 V[14];
#pragma unroll
            for (int t = 0; t < 14; ++t) V[t] = sm.vrt[row][c0 + t];
            vf2 amu[4], aq[4];
#pragma unroll
            for (int i = 0; i < 4; ++i) { amu[i] = (vf2){0.f,0.f}; aq[i] = (vf2){0.f,0.f}; }
#define HT(T) htap<(T)>(V[T], g, amu, aq);
            HT(0) HT(1) HT(2) HT(3) HT(4) HT(5) HT(6)
            HT(7) HT(8) HT(9) HT(10) HT(11) HT(12) HT(13)
#undef HT
            if (oy < Hv) {
#pragma unroll
                for (int i = 0; i < 4; ++i) {
                    int ox = bx + c0 + i;
                    if (ox < Hv) {
                        vf2 mu = amu[i], qq = aq[i];
                        float ab = mu.x * mu.y;
                        vf2 t = mu * mu;
                        float aabb = t.x + t.y;
                        float n1 = fmaf(2.f, ab, 0.0004f);
                        float d1 = aabb + 0.0004f;
                        float v1 = fmaf(2.f, qq.y - ab, 0.0036f);
                        float v2 = (qq.x - aabb) + 0.0036f;
                        float rden = __builtin_amdgcn_rcpf(d1 * v2);
                        cs_l   = fmaf(v1 * d1, rden, cs_l);
                        ssim_l = fmaf(n1 * v1, rden, ssim_l);
                    }
                }
            }
        }
    }

    // ---- block reduction (4 waves) -> one float2 per block
#pragma unroll
    for (int off = 32; off > 0; off >>= 1) {
        ssim_l += __shfl_down(ssim_l, off);
        cs_l   += __shfl_down(cs_l, off);
    }
    int wave = tid >> 6, lane = tid & 63;
    if (lane == 0) { sm.red[wave] = ssim_l; sm.red[4 + wave] = cs_l; }
    __syncthreads();
    if (tid == 0) {
        float ss = sm.red[0] + sm.red[1] + sm.red[2] + sm.red[3];
        float cc = sm.red[4] + sm.red[5] + sm.red[6] + sm.red[7];
        partials[pidx] = make_float2(ss, cc);
    }
}

// ---------------------------------------------------------------------------
__global__ __launch_bounds__(256, 4) void ssim_l0_kernel(
    const float* __restrict__ img1, const float* __restrict__ img2,
    const G11 gw, float2* __restrict__ partials, const PyrOut po)
{
    __shared__ Smem sm;
    int pidx = ((int)blockIdx.z * 16 + (int)blockIdx.y) * 16 + (int)blockIdx.x;
    ssim_body<0>(sm, blockIdx.x, blockIdx.y, blockIdx.z, img1, img2, gw, partials, pidx, &po);
}

__global__ __launch_bounds__(256, 4) void ssim_rest_kernel(
    const G11 gw, float2* __restrict__ partials, const PyrOut po)
{
    __shared__ Smem sm;
    int b = blockIdx.x;
    if (b < 3072) {
        int lb = b;        int z = lb >> 6; int r = lb & 63; int tby = r >> 3; int tbx = r & 7;
        ssim_body<1>(sm, tbx, tby, z, po.a1, po.b1, gw, partials, 12288 + lb, nullptr);
    } else if (b < 3840) {
        int lb = b - 3072; int z = lb >> 4; int r = lb & 15; int tby = r >> 2; int tbx = r & 3;
        ssim_body<2>(sm, tbx, tby, z, po.a2, po.b2, gw, partials, 15360 + lb, nullptr);
    } else if (b < 4032) {
        int lb = b - 3840; int z = lb >> 2; int r = lb & 3;  int tby = r >> 1; int tbx = r & 1;
        ssim_body<3>(sm, tbx, tby, z, po.a3, po.b3, gw, partials, 16128 + lb, nullptr);
    } else {
        int lb = b - 4032;
        ssim_body<4>(sm, 0, 0, lb, po.a4, po.b4, gw, partials, 16320 + lb, nullptr);
    }
}

// ---------------------------------------------------------------------------
// Final reduce: sum per-level partials in double, then msssim formula.
// ---------------------------------------------------------------------------
__global__ __launch_bounds__(1024) void msssim_reduce_kernel(
    const float2* __restrict__ partials, float* __restrict__ out)
{
    __shared__ double sred[16][2];
    __shared__ double lev[10];
    const int NB[5]  = {NB0, NB1, NB2, NB3, NB4};
    const int OFF[5] = {0, NB0, NB0 + NB1, NB0 + NB1 + NB2, NB0 + NB1 + NB2 + NB3};
    const int tid = threadIdx.x;
    const int wv = tid >> 6, ln = tid & 63;

    for (int l = 0; l < 5; ++l) {
        double s = 0.0, c = 0.0;
        for (int i = tid; i < NB[l]; i += 1024) {
            float2 p = partials[OFF[l] + i];
            s += (double)p.x; c += (double)p.y;
        }
#pragma unroll
        for (int off = 32; off > 0; off >>= 1) {
            s += __shfl_down(s, off);
            c += __shfl_down(c, off);
        }
        if (ln == 0) { sred[wv][0] = s; sred[wv][1] = c; }
        __syncthreads();
        if (tid == 0) {
            double ss = 0.0, cc = 0.0;
            for (int w = 0; w < 16; ++w) { ss += sred[w][0]; cc += sred[w][1]; }
            lev[l] = ss; lev[5 + l] = cc;
        }
        __syncthreads();
    }

    if (tid == 0) {
        const double counts[5] = {
            48.0 * 502.0 * 502.0,
            48.0 * 246.0 * 246.0,
            48.0 * 118.0 * 118.0,
            48.0 * 54.0 * 54.0,
            48.0 * 22.0 * 22.0
        };
        const double w[5] = { (double)0.0448f, (double)0.2856f, (double)0.3001f,
                              (double)0.2363f, (double)0.1333f };
        double prod = 1.0;
        for (int i = 0; i < 5; ++i) prod *= pow(lev[i] / counts[i], w[i]);
        double mcs = lev[9] / counts[4];   // cs of LAST level
        double output = pow(mcs, w[4]) * prod;
        out[0] = (float)(1.0 - output);
    }
}

// ---------------------------------------------------------------------------
extern "C" void kernel_launch(void* const* d_in, const int* in_sizes, int n_in,
                              void* d_out, int out_size, void* d_ws, size_t ws_size,
                              hipStream_t stream) {
    const float* img1 = (const float*)d_in[0];
    const float* img2 = (const float*)d_in[1];
    float* out = (float*)d_out;

    // Gaussian taps on host (double, matches numpy f64 -> f32 cast)
    G11 gw;
    {
        double w[11]; double s = 0.0;
        for (int i = 0; i < 11; ++i) { double x = (double)(i - 5); w[i] = std::exp(-(x * x) / 4.5); s += w[i]; }
        for (int i = 0; i < 11; ++i) gw.v[i] = (float)(w[i] / s);
    }

    char* ws = (char*)d_ws;
    float2* partials = (float2*)ws;                    // 16368 float2 = 131 KB
    float* base = (float*)(ws + 131072);
    PyrOut po;
    size_t o = 0;
    po.a1 = base + o; o += (size_t)48 * 65536;
    po.b1 = base + o; o += (size_t)48 * 65536;
    po.a2 = base + o; o += (size_t)48 * 16384;
    po.b2 = base + o; o += (size_t)48 * 16384;
    po.a3 = base + o; o += (size_t)48 * 4096;
    po.b3 = base + o; o += (size_t)48 * 4096;
    po.a4 = base + o; o += (size_t)48 * 1024;
    po.b4 = base + o; o += (size_t)48 * 1024;

    ssim_l0_kernel<<<dim3(16, 16, 48), dim3(256), 0, stream>>>(
        img1, img2, gw, partials, po);

    ssim_rest_kernel<<<dim3(4080), dim3(256), 0, stream>>>(gw, partials, po);

    msssim_reduce_kernel<<<dim3(1), dim3(1024), 0, stream>>>(partials, out);
}